// Round 11
// baseline (1357.916 us; speedup 1.0000x reference)
//
#include <hip/hip_runtime.h>
#include <hip/hip_bf16.h>
#include <cstdint>

// Neural ODE: 10 Heun steps of f(y) = tanh(y@W1 + b1)@W2 + b2
// BATCH=8192, D=512, H=2048, dt=0.1
// R11: R10 (32x32x16 MFMA, merged regions, dbuf hA, 96KB dyn LDS) with the
// two GEMM inner loops FUSED 1:1 inside each steady region. Cycle model from
// R10 counters: VMEM weight stream ~30us and LDS frag reads ~25us per CU per
// f-eval were SERIALIZED (sequential phase blocks = tight dep chains);
// interleaving the independent chains doubles per-wave ILP so both pipes run
// concurrently. Layouts identical to R10 (passed, absmax 0.03125).

#define BATCHN 8192
#define DDIM 512
#define HDIM 2048
#define CW 512          // chunk width over H
#define NCH (HDIM / CW) // 4

typedef short short8 __attribute__((ext_vector_type(8)));
typedef float floatx16 __attribute__((ext_vector_type(16)));

__device__ __forceinline__ unsigned short f2bf(float f) {
  union { __hip_bfloat16 h; unsigned short u; } cv;
  cv.h = __float2bfloat16(f);
  return cv.u;
}

__device__ __forceinline__ float fast_tanh(float x) {
  float e = __expf(2.0f * x);
  return 1.0f - 2.0f / (e + 1.0f);
}

__device__ __forceinline__ void glds16(const void* g, void* l) {
  __builtin_amdgcn_global_load_lds(
      (const __attribute__((address_space(1))) void*)(uintptr_t)g,
      (__attribute__((address_space(3))) void*)(uint32_t)(uintptr_t)l,
      16, 0, 0);
}

// 32x32x16 fragment conventions (verified by R10 passing):
//  A-frag: lane holds A[m = lane&31][k = (lane>>5)*8 + j], j=0..7 (16B)
//  B-frag: lane holds B[n = lane&31][k = (lane>>5)*8 + j]   (BT row-major)
//  C/D:    col = lane&31, row = (reg&3) + 8*(reg>>2) + 4*(lane>>5)
// Packed buffers: frag f at [(f*64 + lane)*8] halves.
//  yPack: f = blk*32 + ks  (blk = batch-row/32, ks = D k-step 0..31)
//  w1p:   f = nb*32 + ks   (nb = H col-tile/32: 0..63,  ks = D k-step 0..31)
//  w2p:   f = nb*128 + kb  (nb = D col-tile/32: 0..15,  kb = H k-step 0..127)

__global__ __launch_bounds__(1024, 4) void fused_feval(
    const unsigned short* __restrict__ yPack,   // packed bf16 eval input
    const unsigned short* __restrict__ w1p,
    const unsigned short* __restrict__ w2p,
    const float* __restrict__ b1,
    const float* __restrict__ b2,
    const float* __restrict__ stateIn,   // EPI1: y fp32 ; EPI2: p fp32
    float* __restrict__ stateOut,        // EPI1: p      ; EPI2: ynew
    unsigned short* __restrict__ outPack,// packed bf16 next-eval input
    int epi) {                           // 1 or 2
  extern __shared__ unsigned short smem[];
  unsigned short* yA    = smem;          // 32 KB: 32 A-frags (ks 0..31)
  unsigned short* hBase = smem + 16384;  // 2 x 32 KB hA double buffer

  const int tid  = threadIdx.x;
  const int lane = tid & 63;
  const int w    = tid >> 6;    // wave 0..15
  const int l31  = lane & 31;
  const int hup  = lane >> 5;   // k-block half (0/1)
  const int blk  = blockIdx.x;  // 0..255
  const int B0   = blk * 32;    // slab base row

  // phase0: linear copy of this block's 32 KB packed y-slab into LDS.
  {
    const unsigned short* src = yPack + (size_t)blk * (32 * 512);
    glds16(src + (size_t)tid * 8, &yA[tid * 8]);
    glds16(src + (size_t)(1024 + tid) * 8, &yA[(1024 + tid) * 8]);
  }
  __syncthreads();

  floatx16 accY = {};  // ymid tile: D cols w*32 + l31

  // scatter/pack helper indices (lane-fixed)
  const int fb  = (l31 >> 4);       // frag sub-index within wave pair
  const int hi  = (l31 & 8) >> 3;   // k-block half of target frag
  const int j7  = l31 & 7;

  // ---- region c=0: phase1 only ----
  {
    floatx16 acc1 = {};
    const unsigned short* w1base = w1p + ((size_t)(0 * 16 + w) * 32) * 512;
#pragma unroll
    for (int ks = 0; ks < 32; ++ks) {
      short8 a = *(const short8*)&yA[(ks * 64 + lane) * 8];
      short8 b = *(const short8*)&w1base[((size_t)ks * 64 + lane) * 8];
      acc1 = __builtin_amdgcn_mfma_f32_32x32x16_bf16(a, b, acc1, 0, 0, 0);
    }
    unsigned short* hbuf = hBase;  // buffer 0
    const float bb = b1[0 * CW + w * 32 + l31];
    const int fbase = w * 2 + fb;
#pragma unroll
    for (int e = 0; e < 16; ++e) {
      const int row = (e & 3) + 8 * (e >> 2) + 4 * hup;
      hbuf[(fbase * 64 + row + 32 * hi) * 8 + j7] =
          f2bf(fast_tanh(acc1[e] + bb));
    }
    __syncthreads();
  }

  // ---- regions c=1..NCH-1: phase1(c) and phase2(c-1) INTERLEAVED 1:1 ----
  for (int c = 1; c < NCH; ++c) {
    floatx16 acc1 = {};
    const unsigned short* w1base = w1p + ((size_t)(c * 16 + w) * 32) * 512;
    const unsigned short* w2base = w2p + ((size_t)(w * 128 + (c - 1) * 32)) * 512;
    const unsigned short* hprev = hBase + ((c - 1) & 1) * 16384;
#pragma unroll
    for (int ks = 0; ks < 32; ++ks) {
      short8 a1 = *(const short8*)&yA[(ks * 64 + lane) * 8];
      short8 b1v = *(const short8*)&w1base[((size_t)ks * 64 + lane) * 8];
      acc1 = __builtin_amdgcn_mfma_f32_32x32x16_bf16(a1, b1v, acc1, 0, 0, 0);
      short8 a2 = *(const short8*)&hprev[(ks * 64 + lane) * 8];
      short8 b2v = *(const short8*)&w2base[((size_t)ks * 64 + lane) * 8];
      accY = __builtin_amdgcn_mfma_f32_32x32x16_bf16(a2, b2v, accY, 0, 0, 0);
    }
    // bias + tanh + scatter chunk c into hBase[c&1]
    {
      unsigned short* hbuf = hBase + (c & 1) * 16384;
      const float bb = b1[c * CW + w * 32 + l31];
      const int fbase = w * 2 + fb;
#pragma unroll
      for (int e = 0; e < 16; ++e) {
        const int row = (e & 3) + 8 * (e >> 2) + 4 * hup;
        hbuf[(fbase * 64 + row + 32 * hi) * 8 + j7] =
            f2bf(fast_tanh(acc1[e] + bb));
      }
    }
    __syncthreads();
  }

  // ---- tail: phase2 for chunk NCH-1 (buffer 1; synced by last barrier) ----
  {
    const unsigned short* hprev = hBase + ((NCH - 1) & 1) * 16384;
    const unsigned short* w2base =
        w2p + ((size_t)(w * 128 + (NCH - 1) * 32)) * 512;
#pragma unroll
    for (int kb = 0; kb < 32; ++kb) {
      short8 a = *(const short8*)&hprev[(kb * 64 + lane) * 8];
      short8 b = *(const short8*)&w2base[((size_t)kb * 64 + lane) * 8];
      accY = __builtin_amdgcn_mfma_f32_32x32x16_bf16(a, b, accY, 0, 0, 0);
    }
  }

  // Epilogue: add b2, Heun combine with fp32 state, pack bf16 result.
  // pbuf = buffer 0: last read was phase2(c=2) inside region c=3 (barriered).
  {
    unsigned short* pbuf = hBase;
    const int ncol = w * 32 + l31;             // D column 0..511
    const float bb = b2[ncol];
    const int fy = w * 2 + fb;                 // outPack frag 0..31
#pragma unroll
    for (int e = 0; e < 16; ++e) {
      const int row = (e & 3) + 8 * (e >> 2) + 4 * hup;  // batch row 0..31
      const size_t idx = (size_t)(B0 + row) * DDIM + ncol;
      const float v = accY[e] + bb;
      float nv;
      if (epi == 1) {
        const float y = stateIn[idx];
        stateOut[idx] = y + 0.05f * v;   // p = y + (dt/2)*k1
        nv = y + 0.1f * v;               // ymid
      } else {
        const float yn = stateIn[idx] + 0.05f * v;  // ynew = p + (dt/2)*k2
        stateOut[idx] = yn;
        nv = yn;
      }
      pbuf[(fy * 64 + row + 32 * hi) * 8 + j7] = f2bf(nv);
    }
    __syncthreads();
    unsigned short* dst = outPack + (size_t)blk * (32 * 512);
#pragma unroll
    for (int p = 0; p < 2; ++p) {
      short8 v = *(const short8*)&pbuf[(size_t)(p * 1024 + tid) * 8];
      *(short8*)&dst[(size_t)(p * 1024 + tid) * 8] = v;
    }
  }
}

// Pack weight [K][N] fp32 -> 32-wide B-frag order: frag f = nb*KB + kb,
// lane entry = src[kb*16 + (lane>>5)*8 + j][nb*32 + (lane&31)].
__global__ void pack_b(const float* __restrict__ src, unsigned short* __restrict__ dst,
                       int KB, int N) {
  const int t = blockIdx.x * 256 + threadIdx.x;
  const int lane = t & 63, f = t >> 6;
  const int nb = f / KB, kb = f % KB;
  const int k0 = kb * 16 + (lane >> 5) * 8, n = nb * 32 + (lane & 31);
  short8 v;
#pragma unroll
  for (int j = 0; j < 8; ++j)
    v[j] = (short)f2bf(src[(size_t)(k0 + j) * N + n]);
  *(short8*)&dst[(size_t)t * 8] = v;
}

// y0 fp32 [8192][512] -> yF fp32 copy + packed bf16 32-wide A-frags.
__global__ void pack_y(const float* __restrict__ y0, float* __restrict__ yF,
                       unsigned short* __restrict__ ypk) {
  const int t = blockIdx.x * 256 + threadIdx.x;
  const int lane = t & 63, f = t >> 6;
  const int bk = f >> 5, ks = f & 31;
  const int row = bk * 32 + (lane & 31), c0 = ks * 16 + (lane >> 5) * 8;
  short8 v;
#pragma unroll
  for (int j = 0; j < 8; ++j) {
    const float x = y0[(size_t)row * DDIM + c0 + j];
    yF[(size_t)row * DDIM + c0 + j] = x;
    v[j] = (short)f2bf(x);
  }
  *(short8*)&ypk[(size_t)t * 8] = v;
}

extern "C" void kernel_launch(void* const* d_in, const int* in_sizes, int n_in,
                              void* d_out, int out_size, void* d_ws, size_t ws_size,
                              hipStream_t stream) {
  const float* y0 = (const float*)d_in[0];
  const float* W1 = (const float*)d_in[1];  // [512][2048]
  const float* b1 = (const float*)d_in[2];  // [2048]
  const float* W2 = (const float*)d_in[3];  // [2048][512]
  const float* b2 = (const float*)d_in[4];  // [512]

  char* ws = (char*)d_ws;
  float*          yF   = (float*)(ws);                         // 16 MB
  float*          pF   = (float*)(ws + (size_t)(16u << 20));   // 16 MB
  unsigned short* ypk  = (unsigned short*)(ws + (size_t)(32u << 20)); // 8 MB
  unsigned short* ympk = (unsigned short*)(ws + (size_t)(40u << 20)); // 8 MB
  unsigned short* w1p  = (unsigned short*)(ws + (size_t)(48u << 20)); // 2 MB
  unsigned short* w2p  = (unsigned short*)(ws + (size_t)(50u << 20)); // 2 MB

  // Allow 96 KB dynamic LDS (host-side attribute; idempotent, capture-safe).
  (void)hipFuncSetAttribute((const void*)fused_feval,
                            hipFuncAttributeMaxDynamicSharedMemorySize, 98304);

  // Pre-pass: pack weights (2048 frags each: W1 64x32, W2 16x128) and y0.
  pack_b<<<512, 256, 0, stream>>>(W1, w1p, 32, HDIM);
  pack_b<<<512, 256, 0, stream>>>(W2, w2p, 128, DDIM);
  pack_y<<<2048, 256, 0, stream>>>(y0, yF, ypk);

  const dim3 grid(256), blkd(1024);
  const size_t shmem = 98304;
  for (int s = 0; s < 10; ++s) {
    // eval1: k1 = f(y); p = y + 0.05*k1; ymid = y + 0.1*k1 (packed)
    fused_feval<<<grid, blkd, shmem, stream>>>(ypk, w1p, w2p, b1, b2, yF, pF, ympk, 1);
    // eval2: k2 = f(ymid); ynew = p + 0.05*k2 (fp32 + packed)
    float* yOut = (s == 9) ? (float*)d_out : yF;
    fused_feval<<<grid, blkd, shmem, stream>>>(ympk, w1p, w2p, b1, b2, pF, yOut, ypk, 2);
  }
}